// Round 1
// baseline (39.677 us; speedup 1.0000x reference)
//
#include <hip/hip_runtime.h>
#include <math.h>

// DeepHit loss: -mean(log(prob+eps)) + 0.5 * mean_pair relu(risk_j - risk_i + 0.1)
// B=8192 rows, T=256 time bins.

#define B_ROWS 8192
#define T_COLS 256

__device__ __constant__ float c_eps    = 1e-8f;
__device__ __constant__ float c_margin = 0.1f;
__device__ __constant__ float c_alpha  = 0.5f;

// ---------------- Stage 1: per-row risk sum + log-prob ----------------
// One block per row, one thread per time bin (T=256).
__global__ __launch_bounds__(256) void row_kernel(
    const float* __restrict__ risk_probs,   // [B, T]
    const int*   __restrict__ times,        // [B]
    const int*   __restrict__ events,       // [B]
    float* __restrict__ risk,               // [B] out: sum_t h
    float* __restrict__ rowll)              // [B] out: log(prob + eps)
{
    const int row = blockIdx.x;
    const int tid = threadIdx.x;

    const float h = risk_probs[row * T_COLS + tid];

    int tb = times[row];
    tb = max(0, min(tb, T_COLS - 1));

    __shared__ float s[256];

    // sum over T for risk
    s[tid] = h;
    __syncthreads();
    for (int off = 128; off > 0; off >>= 1) {
        if (tid < off) s[tid] += s[tid + off];
        __syncthreads();
    }
    const float risksum = s[0];
    __syncthreads();

    // product of (1 - h_i) for i < tb  (== S(t-1), with S(-1)=1)
    s[tid] = (tid < tb) ? (1.0f - h) : 1.0f;
    __syncthreads();
    for (int off = 128; off > 0; off >>= 1) {
        if (tid < off) s[tid] *= s[tid + off];
        __syncthreads();
    }

    if (tid == 0) {
        const float p1 = s[0];                       // S(t-1)
        const float ht = risk_probs[row * T_COLS + tb];  // cached re-read
        const int   ev = events[row];
        // event: S(t-1)*h(t) ; censored: S(t) = S(t-1)*(1-h(t))
        const float prob = p1 * (ev == 1 ? ht : (1.0f - ht));
        risk[row]  = risksum;
        rowll[row] = logf(prob + c_eps);
    }
}

// ---------------- Stage 2: ranking pairs ----------------
// Block i handles all pairs (i, j>i). Writes per-block partials (always,
// since d_ws is poisoned and never re-cleared).
__global__ __launch_bounds__(256) void rank_kernel(
    const float* __restrict__ risk,         // [B]
    const int*   __restrict__ times,        // [B]
    const int*   __restrict__ events,       // [B]
    float*        __restrict__ rank_partial, // [B] out
    unsigned int* __restrict__ cnt_partial)  // [B] out
{
    const int i   = blockIdx.x;
    const int tid = threadIdx.x;

    __shared__ float        s_sum[256];
    __shared__ unsigned int s_cnt[256];

    float        sum = 0.0f;
    unsigned int cnt = 0u;

    if (events[i] == 1) {
        const float ri = risk[i];
        const int   ti = times[i];
        for (int j = i + 1 + tid; j < B_ROWS; j += 256) {
            if (times[j] > ti) {
                const float l = risk[j] - ri + c_margin;
                sum += fmaxf(l, 0.0f);
                cnt += 1u;
            }
        }
    }

    s_sum[tid] = sum;
    s_cnt[tid] = cnt;
    __syncthreads();
    for (int off = 128; off > 0; off >>= 1) {
        if (tid < off) {
            s_sum[tid] += s_sum[tid + off];
            s_cnt[tid] += s_cnt[tid + off];
        }
        __syncthreads();
    }

    if (tid == 0) {
        rank_partial[i] = s_sum[0];
        cnt_partial[i]  = s_cnt[0];
    }
}

// ---------------- Stage 3: deterministic final reduce ----------------
__global__ __launch_bounds__(256) void final_kernel(
    const float*        __restrict__ rowll,         // [B]
    const float*        __restrict__ rank_partial,  // [B]
    const unsigned int* __restrict__ cnt_partial,   // [B]
    float* __restrict__ out)
{
    const int tid = threadIdx.x;

    __shared__ float        s1[256];
    __shared__ float        s2[256];
    __shared__ unsigned int s3[256];

    float        a = 0.0f, b = 0.0f;
    unsigned int c = 0u;
    for (int k = tid; k < B_ROWS; k += 256) {
        a += rowll[k];
        b += rank_partial[k];
        c += cnt_partial[k];
    }
    s1[tid] = a;
    s2[tid] = b;
    s3[tid] = c;
    __syncthreads();
    for (int off = 128; off > 0; off >>= 1) {
        if (tid < off) {
            s1[tid] += s1[tid + off];
            s2[tid] += s2[tid + off];
            s3[tid] += s3[tid + off];
        }
        __syncthreads();
    }

    if (tid == 0) {
        const float ll   = -s1[0] / (float)B_ROWS;
        const float rank = (s3[0] > 0u) ? (s2[0] / (float)s3[0]) : 0.0f;
        out[0] = ll + c_alpha * rank;
    }
}

extern "C" void kernel_launch(void* const* d_in, const int* in_sizes, int n_in,
                              void* d_out, int out_size, void* d_ws, size_t ws_size,
                              hipStream_t stream) {
    const float* risk_probs = (const float*)d_in[0];
    const int*   times      = (const int*)d_in[1];
    const int*   events     = (const int*)d_in[2];
    float*       out        = (float*)d_out;

    // Workspace layout (128 KiB total):
    float*        risk         = (float*)d_ws;                 // [B]
    float*        rowll        = risk + B_ROWS;                // [B]
    float*        rank_partial = rowll + B_ROWS;               // [B]
    unsigned int* cnt_partial  = (unsigned int*)(rank_partial + B_ROWS); // [B]

    row_kernel<<<B_ROWS, 256, 0, stream>>>(risk_probs, times, events, risk, rowll);
    rank_kernel<<<B_ROWS, 256, 0, stream>>>(risk, times, events, rank_partial, cnt_partial);
    final_kernel<<<1, 256, 0, stream>>>(rowll, rank_partial, cnt_partial, out);
}